// Round 9
// baseline (266.327 us; speedup 1.0000x reference)
//
#include <hip/hip_runtime.h>
#include <cstdint>

#define HEADS 16
#define DH 64
#define SEQ 2048
#define BATCH 4
#define DIM 1024
#define MTOT (BATCH*SEQ)   // 8192
#define NQKV (3*DIM)       // 3072

typedef short bf16x8 __attribute__((ext_vector_type(8)));
typedef float f32x4 __attribute__((ext_vector_type(4)));
typedef float f32x16 __attribute__((ext_vector_type(16)));

__device__ __forceinline__ unsigned short f2bf(float f) {
  union { float fv; unsigned int u; } c; c.fv = f;
  unsigned int u = c.u;
  u += 0x7FFFu + ((u >> 16) & 1u);   // round-to-nearest-even
  return (unsigned short)(u >> 16);
}

// pack two fp32 -> two bf16 in one u32 via HW instruction (1 VALU op vs ~5)
// PROVEN: r1-vs-r4 A/B on attention = 11 us (cvtpk vs manual pack)
__device__ __forceinline__ unsigned int cvtpk(float lo, float hi) {
  unsigned int r;
  asm("v_cvt_pk_bf16_f32 %0, %1, %2" : "=v"(r) : "v"(lo), "v"(hi));
  return r;
}

__device__ __forceinline__ f32x4 mfma16(bf16x8 a, bf16x8 b, f32x4 c) {
  return __builtin_amdgcn_mfma_f32_16x16x32_bf16(a, b, c, 0, 0, 0);
}
__device__ __forceinline__ f32x16 mfma32(bf16x8 a, bf16x8 b, f32x16 c) {
  return __builtin_amdgcn_mfma_f32_32x32x16_bf16(a, b, c, 0, 0, 0);
}

typedef const __attribute__((address_space(1))) unsigned int* gas_ptr;
typedef __attribute__((address_space(3))) unsigned int* las_ptr;
__device__ __forceinline__ void gl2lds16(const void* g, void* l) {
  __builtin_amdgcn_global_load_lds((gas_ptr)g, (las_ptr)l, 16, 0, 0);
}

// Q pre-scale: Dh^-0.5 * log2(e)  (softmax done in exp2 domain)
#define QSCALE 0.18033688011112042f

// ---------------------------------------------------------------- cast x -> bf16
__global__ __launch_bounds__(256) void cast_f32_bf16(
    const float* __restrict__ in, unsigned short* __restrict__ out, int n4) {
  int i = blockIdx.x * blockDim.x + threadIdx.x;
  if (i >= n4) return;
  float4 v = reinterpret_cast<const float4*>(in)[i];
  uint2 o;
  o.x = (unsigned int)f2bf(v.x) | ((unsigned int)f2bf(v.y) << 16);
  o.y = (unsigned int)f2bf(v.z) | ((unsigned int)f2bf(v.w) << 16);
  reinterpret_cast<uint2*>(out)[i] = o;
}

// ------------------------------------------- transpose+cast: out[c][r] = in[r][c]
__global__ __launch_bounds__(256) void transpose_cast(
    const float* __restrict__ in, unsigned short* __restrict__ out, int R, int C) {
  __shared__ float tile[32][33];
  int c0 = blockIdx.x * 32, r0 = blockIdx.y * 32;
  int tx = threadIdx.x & 31, ty = threadIdx.x >> 5;  // ty 0..7
  for (int i = 0; i < 32; i += 8)
    tile[ty + i][tx] = in[(size_t)(r0 + ty + i) * C + c0 + tx];
  __syncthreads();
  for (int i = 0; i < 32; i += 8)
    out[(size_t)(c0 + ty + i) * R + r0 + tx] = f2bf(tile[tx][ty + i]);
}

// ================================================================ pipelined GEMM (ring-3)
// 256x128 tile, BK=64, 512 threads = 8 waves (4M x 2N), wave tile 64x64 =
// acc[4][4] — fragment read logic IDENTICAL to the r5-proven kernel
// (read chunk = (ks*4+fg)^(fr&7), both-sides XOR swizzle via pre-swizzled
// global source, linear gl2lds dest).
// RING-3 LDS: 3 bufs x (A 256x64 = 32KB | B 128x64 = 16KB) = 144KB.
// Tile T+2 staged (6 gl2lds/thread-group) while computing T -> 2-tile
// prefetch lead. Entry: counted vmcnt(6) (T+1's 6 loads stay in flight,
// NEVER drained) + raw s_barrier. One mid-tile phasing barrier. Tail peeled
// with vmcnt(0). Race-freedom: stages into buf b issue only after the
// entry barrier that follows the last reads of b (ring rotation).
// NT = K/64 = 16 for both GEMMs.

#define PG_SETUP(Abase, Bbase) \
  int t = threadIdx.x; \
  int lane = t & 63, w = t >> 6; \
  int wm64 = (w >> 1) * 64, wn64 = (w & 1) * 64; \
  int fr = lane & 15, fg = lane >> 4; \
  const unsigned short* gAs = (Abase) + (size_t)(m0 + (t >> 3)) * 1024 \
                              + ((t & 7) ^ ((t >> 3) & 7)) * 8; \
  const unsigned short* gBs = (Bbase) + (size_t)(n0 + (t >> 3)) * 1024 \
                              + ((t & 7) ^ ((t >> 3) & 7)) * 8; \
  char* lds_c = (char*)smem + t * 16; \
  f32x4 acc[4][4]; \
  _Pragma("unroll") \
  for (int i = 0; i < 4; i++) \
    _Pragma("unroll") \
    for (int j = 0; j < 4; j++) { f32x4 z = {0.f, 0.f, 0.f, 0.f}; acc[i][j] = z; }

// stage A-half H (rows H*128..H*128+127) of K-tile TT into ring buffer SB
#define PG_STAGE_AH(SB, TT, H) { \
    gl2lds16(gAs + (H) * 128 * 1024 + (TT) * 64, \
             lds_c + (SB) * 49152 + (H) * 16384); \
    gl2lds16(gAs + ((H) * 128 + 64) * 1024 + (TT) * 64, \
             lds_c + (SB) * 49152 + (H) * 16384 + 8192); }

#define PG_STAGE_B(SB, TT) { \
    gl2lds16(gBs + (TT) * 64, lds_c + (SB) * 49152 + 32768); \
    gl2lds16(gBs + 64 * 1024 + (TT) * 64, lds_c + (SB) * 49152 + 32768 + 8192); }

// one K-sub-step (KS in {0,1}): 8 ds_read_b128 + 16 MFMA under setprio
#define PG_PHASE(SB, KS) { \
    const unsigned short* sAb = smem + (SB) * 24576; \
    const unsigned short* sBb = sAb + 16384; \
    bf16x8 af[4], bv[4]; \
    _Pragma("unroll") \
    for (int mt = 0; mt < 4; mt++) \
      af[mt] = *reinterpret_cast<const bf16x8*>( \
          &sAb[(wm64 + mt * 16 + fr) * 64 + (((KS) * 4 + fg) ^ (fr & 7)) * 8]); \
    _Pragma("unroll") \
    for (int nt = 0; nt < 4; nt++) \
      bv[nt] = *reinterpret_cast<const bf16x8*>( \
          &sBb[(wn64 + nt * 16 + fr) * 64 + (((KS) * 4 + fg) ^ (fr & 7)) * 8]); \
    __builtin_amdgcn_s_setprio(1); \
    _Pragma("unroll") \
    for (int mt = 0; mt < 4; mt++) \
      _Pragma("unroll") \
      for (int nt = 0; nt < 4; nt++) \
        acc[mt][nt] = mfma16(af[mt], bv[nt], acc[mt][nt]); \
    __builtin_amdgcn_s_setprio(0); }

#define PG_MAIN { \
    PG_STAGE_AH(0, 0, 0); PG_STAGE_AH(0, 0, 1); PG_STAGE_B(0, 0); \
    PG_STAGE_AH(1, 1, 0); PG_STAGE_AH(1, 1, 1); PG_STAGE_B(1, 1); \
    int buf = 0, sb = 2; \
    _Pragma("unroll 1") \
    for (int T = 0; T < 15; ++T) { \
      asm volatile("s_waitcnt vmcnt(6)" ::: "memory"); \
      __builtin_amdgcn_s_barrier(); \
      __builtin_amdgcn_sched_barrier(0); \
      if (T < 14) PG_STAGE_AH(sb, T + 2, 0); \
      PG_PHASE(buf, 0); \
      __builtin_amdgcn_s_barrier(); \
      if (T < 14) { PG_STAGE_AH(sb, T + 2, 1); PG_STAGE_B(sb, T + 2); } \
      PG_PHASE(buf, 1); \
      buf = (buf == 2) ? 0 : buf + 1; \
      sb = (sb == 2) ? 0 : sb + 1; \
    } \
    asm volatile("s_waitcnt vmcnt(0)" ::: "memory"); \
    __builtin_amdgcn_s_barrier(); \
    __builtin_amdgcn_sched_barrier(0); \
    PG_PHASE(0, 0); /* tile 15 -> buf 15%3 == 0 */ \
    PG_PHASE(0, 1); }

// ---------------------------------------------------------------- QKV GEMM
__global__ __launch_bounds__(512) void gemm_qkv(
    const unsigned short* __restrict__ A, const unsigned short* __restrict__ Bt,
    unsigned short* __restrict__ Q, unsigned short* __restrict__ K,
    unsigned short* __restrict__ V) {
  __shared__ unsigned short smem[73728];   // 144KB ring-3
  // grid (24, 32): 768 blocks = exactly 3.0 CU-rounds. XCD-bijective swizzle.
  int gid = blockIdx.x + 24 * blockIdx.y;
  int swz = (gid & 7) * 96 + (gid >> 3);   // cpx = 768/8
  int m0 = (swz / 24) * 256;
  int n0 = (swz % 24) * 128;

  PG_SETUP(A, Bt)
  PG_MAIN

  // epilogue (r8-proven pattern): Q,K -> [b][h][n][d]; V -> V^T [b][h][d][n]
  // via per-wave LDS-coalesced stores. Scratch lives in ring-buf 1 region
  // (shorts 24576..): last tile used buf 0, so buf 1 is idle for all waves.
  int rowq = fg * 4;
  int b = m0 >> 11;                       // block-uniform (256 | 2048)
  int nrow0 = (m0 & 2047) + wm64 + rowq;
#pragma unroll
  for (int nt = 0; nt < 4; nt++) {
    int ncb = n0 + wn64 + nt * 16;        // lane-uniform column base
    int which = ncb >> 10;                // uniform: fr<16 can't cross 1024
    int hdb = ncb & 1023;
    int hh = hdb >> 6;                    // uniform: (n0+wn64)%64==0
    if (which == 2) {
      unsigned short* tw = smem + 24576 + ((nt & 1) ? 9216 : 0) + w * 1152;
#pragma unroll
      for (int mt = 0; mt < 4; mt++) {
        f32x4 av = acc[mt][nt];
        uint2 pk;
        pk.x = cvtpk(av[0], av[1]);
        pk.y = cvtpk(av[2], av[3]);
        // d = fr, m-local = mt*16 + fg*4 + {0..3}
        *(uint2*)&tw[fr * 72 + mt * 16 + fg * 4] = pk;
      }
      int dr = lane >> 2, sg = lane & 3;   // 16 d-rows x 4 lanes (8-short segs)
      size_t vrow = ((size_t)(b * HEADS + hh) * DH + nt * 16 + dr) * SEQ
                  + (m0 & 2047) + wm64 + sg * 8;
#pragma unroll
      for (int it = 0; it < 2; it++) {
        uint4 vv = *(const uint4*)&tw[dr * 72 + sg * 8 + it * 32];
        *(uint4*)&V[vrow + it * 32] = vv;
      }
    } else {
      int dcol = (hdb & 63) + fr;
      unsigned short* dst = (which == 0) ? Q : K;
      size_t cbase = ((size_t)(b * HEADS + hh) * SEQ) * DH + dcol;
#pragma unroll
      for (int mt = 0; mt < 4; mt++) {
        f32x4 av = acc[mt][nt];
        if (which == 0) {                 // uniform branch (Q pre-scale)
          av[0] *= QSCALE; av[1] *= QSCALE; av[2] *= QSCALE; av[3] *= QSCALE;
        }
        size_t idx = cbase + (size_t)(nrow0 + mt * 16) * DH;
        unsigned int u0 = cvtpk(av[0], av[1]);
        unsigned int u1 = cvtpk(av[2], av[3]);
        dst[idx]          = (unsigned short)u0;
        dst[idx + DH]     = (unsigned short)(u0 >> 16);
        dst[idx + 2 * DH] = (unsigned short)u1;
        dst[idx + 3 * DH] = (unsigned short)(u1 >> 16);
      }
    }
  }
}

// ---------------------------------------------------------------- out-proj GEMM
__global__ __launch_bounds__(512) void gemm_out(
    const unsigned short* __restrict__ A, const unsigned short* __restrict__ Bt,
    const float* __restrict__ bias, float* __restrict__ C) {
  __shared__ unsigned short smem[73728];   // 144KB ring-3
  // grid (8, 32): 256 blocks = exactly 1.0 CU-round. XCD-bijective swizzle.
  int gid = blockIdx.x + 8 * blockIdx.y;
  int swz = (gid & 7) * 32 + (gid >> 3);   // cpx = 256/8
  int m0 = (swz / 8) * 256;
  int n0 = (swz % 8) * 128;

  PG_SETUP(A, Bt)
  PG_MAIN

  // epilogue: hoisted addressing; bias loaded once per nt
  int rowq = fg * 4;
#pragma unroll
  for (int nt = 0; nt < 4; nt++) {
    int ncol = n0 + wn64 + nt * 16 + fr;
    float bb = bias[ncol];
    size_t cb = (size_t)(m0 + wm64 + rowq) * DIM + ncol;
#pragma unroll
    for (int mt = 0; mt < 4; mt++)
#pragma unroll
      for (int r = 0; r < 4; r++)
        C[cb + (size_t)(mt * 16 + r) * DIM] = acc[mt][nt][r] + bb;
  }
}

// ---------------------------------------------------------------- flash attention
// ROUND-8 EXACT (83 us): cvtpk packing, single-buffer, 2 barriers/tile,
// setprio around MFMA clusters. grid (SEQ/128, HEADS, BATCH), XCD-grouped.
#define LDA 68

__global__ __launch_bounds__(256, 4) void attention(
    const unsigned short* __restrict__ Qg, const unsigned short* __restrict__ Kg,
    const unsigned short* __restrict__ Vtg, unsigned short* __restrict__ Og) {
  __shared__ unsigned short smem[2 * 64 * 72];   // 18432 B
  unsigned short* sK  = smem;
  unsigned short* sVt = smem + 64 * LDA;

  int gid = blockIdx.x + 16 * (blockIdx.y + 16 * blockIdx.z);  // 0..1023
  int qb   = (gid >> 3) & 15;
  int pair = ((gid & 7) << 3) | (gid >> 7);   // xcd*8 + group
  int h = pair & 15, b = pair >> 4;

  size_t base = (size_t)(b * HEADS + h) * SEQ * DH;
  const unsigned short* Q = Qg + base;
  const unsigned short* K = Kg + base;
  const unsigned short* Vt = Vtg + base;
  int t = threadIdx.x, lane = t & 63, w = t >> 6;
  int m = lane & 31, kh = lane >> 5;
  int q0 = qb * 128 + w * 32;

  bf16x8 qf[4];
#pragma unroll
  for (int kt = 0; kt < 4; kt++)
    qf[kt] = *reinterpret_cast<const bf16x8*>(
        &Q[(size_t)(q0 + m) * DH + kt * 16 + kh * 8]);

  f32x16 oaccT[2];   // [dhalf], C layout: row=d', col=qrow
#pragma unroll
  for (int dh = 0; dh < 2; dh++)
#pragma unroll
    for (int i = 0; i < 16; i++) oaccT[dh][i] = 0.f;
  float rs = 0.f;

  int sr = t >> 2, sc = (t & 3) * 8;

  for (int j0 = 0; j0 < SEQ; j0 += 64) {
    {
      uint4 a0 = *(const uint4*)&K[(size_t)(j0 + sr) * DH + sc];
      uint4 a1 = *(const uint4*)&K[(size_t)(j0 + sr) * DH + sc + 32];
      uint4 b0 = *(const uint4*)&Vt[(size_t)sr * SEQ + j0 + sc];
      uint4 b1 = *(const uint4*)&Vt[(size_t)sr * SEQ + j0 + sc + 32];
      unsigned short* pk0 = &sK[sr * LDA + sc];
      unsigned short* pk1 = &sK[sr * LDA + sc + 32];
      unsigned short* pv0 = &sVt[sr * LDA + sc];
      unsigned short* pv1 = &sVt[sr * LDA + sc + 32];
      *(uint2*)pk0       = make_uint2(a0.x, a0.y);
      *(uint2*)(pk0 + 4) = make_uint2(a0.z, a0.w);
      *(uint2*)pk1       = make_uint2(a1.x, a1.y);
      *(uint2*)(pk1 + 4) = make_uint2(a1.z, a1.w);
      *(uint2*)pv0       = make_uint2(b0.x, b0.y);
      *(uint2*)(pv0 + 4) = make_uint2(b0.z, b0.w);
      *(uint2*)pv1       = make_uint2(b1.x, b1.y);
      *(uint2*)(pv1 + 4) = make_uint2(b1.z, b1.w);
    }
    __syncthreads();

    unsigned int pp[8][2];
#pragma unroll
    for (int jt = 0; jt < 2; jt++) {
      bf16x8 kf[4];
#pragma unroll
      for (int kt = 0; kt < 4; kt++) {
        union { uint2 u[2]; bf16x8 v; } kc;
        const unsigned short* p = &sK[(jt * 32 + m) * LDA + (2 * kt + kh) * 8];
        kc.u[0] = *(const uint2*)p;
        kc.u[1] = *(const uint2*)(p + 4);
        kf[kt] = kc.v;
      }
      f32x16 s;
#pragma unroll
      for (int i = 0; i < 16; i++) s[i] = 0.f;
      __builtin_amdgcn_s_setprio(1);
#pragma unroll
      for (int kt = 0; kt < 4; kt++)
        s = mfma32(kf[kt], qf[kt], s);
      __builtin_amdgcn_s_setprio(0);
      float e[16];
#pragma unroll
      for (int i = 0; i < 16; i++) e[i] = __builtin_amdgcn_exp2f(s[i]);
      float t0 = (e[0] + e[1]) + (e[2] + e[3]);
      float t1 = (e[4] + e[5]) + (e[6] + e[7]);
      float t2 = (e[8] + e[9]) + (e[10] + e[11]);
      float t3 = (e[12] + e[13]) + (e[14] + e[15]);
      rs += (t0 + t1) + (t2 + t3);
#pragma unroll
      for (int sl = 0; sl < 4; sl++) {
        pp[4 * jt + sl][0] = cvtpk(e[4 * sl + 0], e[4 * sl + 1]);
        pp[4 * jt + sl][1] = cvtpk(e[4 * sl + 2], e[4 * sl + 3]);
      }
    }

    __builtin_amdgcn_s_setprio(1);
#pragma unroll
    for (int kb = 0; kb < 4; kb++) {
#pragma unroll
      for (int dh = 0; dh < 2; dh++) {
        union { uint2 u[2]; bf16x8 v; } ac;
        const unsigned short* p = &sVt[(32 * dh + m) * LDA + 16 * kb + 4 * kh];
        ac.u[0] = *(const uint2*)p;
        ac.u[1] = *(const uint2*)(p + 8);
        union { unsigned int u[4]; bf16x8 v; } bc;
        bc.u[0] = pp[2 * kb][0];
        bc.u[1] = pp[2 * kb][1];
        bc.u[2] = pp[2 * kb + 1][0];
        bc.u[3] = pp[2 * kb + 1][1];
        oaccT[dh] = mfma32(ac.v, bc.v, oaccT[dh]);
      }
    }
    __builtin_amdgcn_s_setprio(0);
    __syncthreads();
  }

  float inv;
  {
    float tot = rs + __shfl_xor(rs, 32);
    inv = 1.0f / tot;
  }

  unsigned int* ew = (unsigned int*)smem + (size_t)w * 32 * 36;
#pragma unroll
  for (int dh = 0; dh < 2; dh++)
#pragma unroll
    for (int sl = 0; sl < 4; sl++) {
      unsigned int u0 = cvtpk(oaccT[dh][4 * sl + 0] * inv, oaccT[dh][4 * sl + 1] * inv);
      unsigned int u1 = cvtpk(oaccT[dh][4 * sl + 2] * inv, oaccT[dh][4 * sl + 3] * inv);
      uint2 pk; pk.x = u0; pk.y = u1;
      *(uint2*)&ew[m * 36 + 16 * dh + 4 * sl + 2 * kh] = pk;
    }
  {
    int mr = lane >> 3, ch = lane & 7;
#pragma unroll
    for (int it = 0; it < 4; it++) {
      uint4 vv = *(const uint4*)&ew[(8 * it + mr) * 36 + ch * 4];
      int n = q0 + 8 * it + mr;
      *(uint4*)&Og[((size_t)(b * SEQ + n)) * DIM + h * DH + ch * 8] = vv;
    }
  }
}

// ---------------------------------------------------------------- launch
extern "C" void kernel_launch(void* const* d_in, const int* in_sizes, int n_in,
                              void* d_out, int out_size, void* d_ws, size_t ws_size,
                              hipStream_t stream) {
  const float* x     = (const float*)d_in[0];  // [4,2048,1024]
  const float* w_qkv = (const float*)d_in[1];  // [1024,3072]
  const float* w_out = (const float*)d_in[2];  // [1024,1024]
  const float* b_out = (const float*)d_in[3];  // [1024]
  float* out = (float*)d_out;                  // [4,2048,1024]

  char* ws = (char*)d_ws;
  unsigned short* xb     = (unsigned short*)ws; ws += (size_t)MTOT * DIM * 2;
  unsigned short* wqkv_t = (unsigned short*)ws; ws += (size_t)NQKV * DIM * 2;
  unsigned short* wout_t = (unsigned short*)ws; ws += (size_t)DIM * DIM * 2;
  unsigned short* qb_    = (unsigned short*)ws; ws += (size_t)BATCH * HEADS * SEQ * DH * 2;
  unsigned short* kb_    = (unsigned short*)ws; ws += (size_t)BATCH * HEADS * SEQ * DH * 2;
  unsigned short* vtb_   = (unsigned short*)ws; ws += (size_t)BATCH * HEADS * SEQ * DH * 2;
  unsigned short* attnb  = (unsigned short*)ws; ws += (size_t)MTOT * DIM * 2;

  // 1. casts / transposes
  cast_f32_bf16<<<(MTOT * DIM / 4 + 255) / 256, 256, 0, stream>>>(x, xb, MTOT * DIM / 4);
  transpose_cast<<<dim3(NQKV / 32, DIM / 32), 256, 0, stream>>>(w_qkv, wqkv_t, DIM, NQKV);
  transpose_cast<<<dim3(DIM / 32, DIM / 32), 256, 0, stream>>>(w_out, wout_t, DIM, DIM);

  // 2. QKV projection — ring-3 pipelined 256x128 (768 blocks = 3.0 rounds);
  //    Q,K [b,h,n,d]; V TRANSPOSED [b,h,d,n] via LDS-coalesced epilogue
  gemm_qkv<<<dim3(24, 32), 512, 0, stream>>>(xb, wqkv_t, qb_, kb_, vtb_);

  // 3. flash attention (register-resident P, r8 structure)
  attention<<<dim3(SEQ / 128, HEADS, BATCH), 256, 0, stream>>>(qb_, kb_, vtb_, attnb);

  // 4. output projection — ring-3 pipelined 256x128 (256 blocks = 1.0 round)
  gemm_out<<<dim3(8, 32), 512, 0, stream>>>(attnb, wout_t, b_out, out);
}

// Round 10
// 258.975 us; speedup vs baseline: 1.0284x; 1.0284x over previous
//
#include <hip/hip_runtime.h>
#include <cstdint>

#define HEADS 16
#define DH 64
#define SEQ 2048
#define BATCH 4
#define DIM 1024
#define MTOT (BATCH*SEQ)   // 8192
#define NQKV (3*DIM)       // 3072

typedef short bf16x8 __attribute__((ext_vector_type(8)));
typedef float f32x4 __attribute__((ext_vector_type(4)));
typedef float f32x16 __attribute__((ext_vector_type(16)));

__device__ __forceinline__ unsigned short f2bf(float f) {
  union { float fv; unsigned int u; } c; c.fv = f;
  unsigned int u = c.u;
  u += 0x7FFFu + ((u >> 16) & 1u);   // round-to-nearest-even
  return (unsigned short)(u >> 16);
}

// pack two fp32 -> two bf16 in one u32 via HW instruction (1 VALU op vs ~5)
// PROVEN: r1-vs-r4 A/B on attention = 11 us (cvtpk vs manual pack)
__device__ __forceinline__ unsigned int cvtpk(float lo, float hi) {
  unsigned int r;
  asm("v_cvt_pk_bf16_f32 %0, %1, %2" : "=v"(r) : "v"(lo), "v"(hi));
  return r;
}

__device__ __forceinline__ f32x4 mfma16(bf16x8 a, bf16x8 b, f32x4 c) {
  return __builtin_amdgcn_mfma_f32_16x16x32_bf16(a, b, c, 0, 0, 0);
}
__device__ __forceinline__ f32x16 mfma32(bf16x8 a, bf16x8 b, f32x16 c) {
  return __builtin_amdgcn_mfma_f32_32x32x16_bf16(a, b, c, 0, 0, 0);
}

typedef const __attribute__((address_space(1))) unsigned int* gas_ptr;
typedef __attribute__((address_space(3))) unsigned int* las_ptr;
__device__ __forceinline__ void gl2lds16(const void* g, void* l) {
  __builtin_amdgcn_global_load_lds((gas_ptr)g, (las_ptr)l, 16, 0, 0);
}

// Q pre-scale: Dh^-0.5 * log2(e)  (softmax done in exp2 domain)
#define QSCALE 0.18033688011112042f

// ---------------------------------------------------------------- cast x -> bf16
// 8 floats/thread (2x float4 in, 1x uint4 out) — G13 vectorization.
__global__ __launch_bounds__(256) void cast_f32_bf16(
    const float* __restrict__ in, unsigned short* __restrict__ out, int n8) {
  int i = blockIdx.x * blockDim.x + threadIdx.x;
  if (i >= n8) return;
  float4 v0 = reinterpret_cast<const float4*>(in)[2 * i];
  float4 v1 = reinterpret_cast<const float4*>(in)[2 * i + 1];
  uint4 o;
  o.x = cvtpk(v0.x, v0.y);
  o.y = cvtpk(v0.z, v0.w);
  o.z = cvtpk(v1.x, v1.y);
  o.w = cvtpk(v1.z, v1.w);
  reinterpret_cast<uint4*>(out)[i] = o;
}

// ------------------------------------------- transpose+cast: out[c][r] = in[r][c]
__global__ __launch_bounds__(256) void transpose_cast(
    const float* __restrict__ in, unsigned short* __restrict__ out, int R, int C) {
  __shared__ float tile[32][33];
  int c0 = blockIdx.x * 32, r0 = blockIdx.y * 32;
  int tx = threadIdx.x & 31, ty = threadIdx.x >> 5;  // ty 0..7
  for (int i = 0; i < 32; i += 8)
    tile[ty + i][tx] = in[(size_t)(r0 + ty + i) * C + c0 + tx];
  __syncthreads();
  for (int i = 0; i < 32; i += 8)
    out[(size_t)(c0 + ty + i) * R + r0 + tx] = f2bf(tile[tx][ty + i]);
}

// ---------------------------------------------------------------- QKV GEMM
// r8-proven: m97 structure, BK=64, XOR-swizzled tiles (both-sides pattern),
// hoisted epilogue. V written TRANSPOSED [b,h,d,n] via per-wave LDS transpose
// tile -> 64B-coalesced uint4 stores (r8: -8.5 us vs direct scatter).
#define BM 128
#define BN 128
#define BK 64

__global__ __launch_bounds__(256) void gemm_qkv(
    const unsigned short* __restrict__ A, const unsigned short* __restrict__ Bt,
    unsigned short* __restrict__ Q, unsigned short* __restrict__ K,
    unsigned short* __restrict__ V) {
  __shared__ unsigned short sA[BM * BK];
  __shared__ unsigned short sB[BN * BK];
  const int KD = 1024;
  // XCD-bijective swizzle (nwg = 24*64 = 1536, %8==0)
  int gid = blockIdx.x + 24 * blockIdx.y;      // gridDim.x == 24
  int swz = (gid & 7) * 192 + (gid >> 3);      // cpx = 1536/8
  int m0 = (swz / 24) * BM;
  int n0 = (swz % 24) * BN;
  int t = threadIdx.x;
  int lane = t & 63, w = t >> 6;
  int wm = (w >> 1) * 64, wn = (w & 1) * 64;
  int fr = lane & 15, fg = lane >> 4;

  // staging: wave w, issue i covers rows i*32 + w*8 + (lane>>3);
  // global col chunk = (lane&7) ^ (lane>>3)  (pre-swizzled source)
  int srow = w * 8 + (lane >> 3);
  int scol = ((lane & 7) ^ (lane >> 3)) * 8;
  const unsigned short* gA = &A[(size_t)(m0 + srow) * KD + scol];
  const unsigned short* gB = &Bt[(size_t)(n0 + srow) * KD + scol];
  char* lA = (char*)sA + w * 1024;   // + i*4096 per issue; lane*16 implicit
  char* lB = (char*)sB + w * 1024;

  f32x4 acc[4][4];
#pragma unroll
  for (int i = 0; i < 4; i++)
#pragma unroll
    for (int j = 0; j < 4; j++) { f32x4 z = {0.f, 0.f, 0.f, 0.f}; acc[i][j] = z; }

  for (int k0 = 0; k0 < KD; k0 += BK) {
#pragma unroll
    for (int i = 0; i < 4; i++) {
      gl2lds16(gA + (size_t)i * 32 * KD + k0, lA + i * 4096);
      gl2lds16(gB + (size_t)i * 32 * KD + k0, lB + i * 4096);
    }
    __syncthreads();
#pragma unroll
    for (int ks = 0; ks < 2; ks++) {
      bf16x8 af[4], bfr[4];
#pragma unroll
      for (int mt = 0; mt < 4; mt++)
        af[mt] = *reinterpret_cast<const bf16x8*>(
            &sA[(wm + mt * 16 + fr) * BK + (((ks * 4 + fg) ^ (fr & 7)) * 8)]);
#pragma unroll
      for (int nt = 0; nt < 4; nt++)
        bfr[nt] = *reinterpret_cast<const bf16x8*>(
            &sB[(wn + nt * 16 + fr) * BK + (((ks * 4 + fg) ^ (fr & 7)) * 8)]);
#pragma unroll
      for (int mt = 0; mt < 4; mt++)
#pragma unroll
        for (int nt = 0; nt < 4; nt++)
          acc[mt][nt] = mfma16(af[mt], bfr[nt], acc[mt][nt]);
    }
    __syncthreads();
  }
  // NOTE: final __syncthreads above -> all waves done with sA/sB; safe to
  // reuse sA/sB as per-wave epilogue scratch below.

  // epilogue: Q,K -> [b][h][n][d]; V -> TRANSPOSED [b][h][d][n]
  int rowq = fg * 4;
  int b = m0 >> 11;                       // block-uniform (BM=128 | 2048)
  int nrow0 = (m0 & 2047) + wm + rowq;    // + mt*16, no wrap within block
#pragma unroll
  for (int nt = 0; nt < 4; nt++) {
    int ncb = n0 + wn + nt * 16;          // lane-uniform column base
    int which = ncb >> 10;                // uniform: fr<16 can't cross 1024
    int hdb = ncb & 1023;
    int hh = hdb >> 6;                    // uniform: (n0+wn)%64==0
    if (which == 2) {
      // V^T path: assemble wave's 16(d) x 64(m) subtile in LDS, then
      // 64B-coalesced uint4 stores. Tile 16x72 shorts (rows 144B, 16B-aligned;
      // write conflicts 2-way = free; reads min-conflict). Per-wave private,
      // within-wave ds ordering suffices (no barrier). Alternate sA/sB per nt.
      unsigned short* tw = ((nt & 1) ? sB : sA) + w * 1152;
#pragma unroll
      for (int mt = 0; mt < 4; mt++) {
        f32x4 av = acc[mt][nt];
        uint2 pk;
        pk.x = cvtpk(av[0], av[1]);
        pk.y = cvtpk(av[2], av[3]);
        // d = fr, m-local = mt*16 + fg*4 + {0..3}
        *(uint2*)&tw[fr * 72 + mt * 16 + fg * 4] = pk;
      }
      int dr = lane >> 2, sg = lane & 3;   // 16 d-rows x 4 lanes (8-short segs)
      size_t vrow = ((size_t)(b * HEADS + hh) * DH + nt * 16 + dr) * SEQ
                  + (m0 & 2047) + wm + sg * 8;
#pragma unroll
      for (int it = 0; it < 2; it++) {
        uint4 vv = *(const uint4*)&tw[dr * 72 + sg * 8 + it * 32];
        *(uint4*)&V[vrow + it * 32] = vv;
      }
    } else {
      int dcol = (hdb & 63) + fr;
      unsigned short* dst = (which == 0) ? Q : K;
      size_t cbase = ((size_t)(b * HEADS + hh) * SEQ) * DH + dcol;
#pragma unroll
      for (int mt = 0; mt < 4; mt++) {
        f32x4 av = acc[mt][nt];
        if (which == 0) {                 // uniform branch (Q pre-scale)
          av[0] *= QSCALE; av[1] *= QSCALE; av[2] *= QSCALE; av[3] *= QSCALE;
        }
        size_t idx = cbase + (size_t)(nrow0 + mt * 16) * DH;
        unsigned int u0 = cvtpk(av[0], av[1]);
        unsigned int u1 = cvtpk(av[2], av[3]);
        dst[idx]          = (unsigned short)u0;
        dst[idx + DH]     = (unsigned short)(u0 >> 16);
        dst[idx + 2 * DH] = (unsigned short)u1;
        dst[idx + 3 * DH] = (unsigned short)(u1 >> 16);
      }
    }
  }
}

// ---------------------------------------------------------------- out-proj GEMM
__global__ __launch_bounds__(256) void gemm_out(
    const unsigned short* __restrict__ A, const unsigned short* __restrict__ Bt,
    const float* __restrict__ bias, float* __restrict__ C) {
  __shared__ unsigned short sA[BM * BK];
  __shared__ unsigned short sB[BN * BK];
  const int KD = 1024;
  // XCD-bijective swizzle (nwg = 8*64 = 512, %8==0)
  int gid = blockIdx.x + 8 * blockIdx.y;       // gridDim.x == 8
  int swz = (gid & 7) * 64 + (gid >> 3);       // cpx = 512/8
  int m0 = (swz / 8) * BM;
  int n0 = (swz % 8) * BN;
  int t = threadIdx.x;
  int lane = t & 63, w = t >> 6;
  int wm = (w >> 1) * 64, wn = (w & 1) * 64;
  int fr = lane & 15, fg = lane >> 4;

  int srow = w * 8 + (lane >> 3);
  int scol = ((lane & 7) ^ (lane >> 3)) * 8;
  const unsigned short* gA = &A[(size_t)(m0 + srow) * KD + scol];
  const unsigned short* gB = &Bt[(size_t)(n0 + srow) * KD + scol];
  char* lA = (char*)sA + w * 1024;
  char* lB = (char*)sB + w * 1024;

  f32x4 acc[4][4];
#pragma unroll
  for (int i = 0; i < 4; i++)
#pragma unroll
    for (int j = 0; j < 4; j++) { f32x4 z = {0.f, 0.f, 0.f, 0.f}; acc[i][j] = z; }

  for (int k0 = 0; k0 < KD; k0 += BK) {
#pragma unroll
    for (int i = 0; i < 4; i++) {
      gl2lds16(gA + (size_t)i * 32 * KD + k0, lA + i * 4096);
      gl2lds16(gB + (size_t)i * 32 * KD + k0, lB + i * 4096);
    }
    __syncthreads();
#pragma unroll
    for (int ks = 0; ks < 2; ks++) {
      bf16x8 af[4], bfr[4];
#pragma unroll
      for (int mt = 0; mt < 4; mt++)
        af[mt] = *reinterpret_cast<const bf16x8*>(
            &sA[(wm + mt * 16 + fr) * BK + (((ks * 4 + fg) ^ (fr & 7)) * 8)]);
#pragma unroll
      for (int nt = 0; nt < 4; nt++)
        bfr[nt] = *reinterpret_cast<const bf16x8*>(
            &sB[(wn + nt * 16 + fr) * BK + (((ks * 4 + fg) ^ (fr & 7)) * 8)]);
#pragma unroll
      for (int mt = 0; mt < 4; mt++)
#pragma unroll
        for (int nt = 0; nt < 4; nt++)
          acc[mt][nt] = mfma16(af[mt], bfr[nt], acc[mt][nt]);
    }
    __syncthreads();
  }

  // epilogue: hoisted addressing; bias loaded once per nt
  int rowq = (lane >> 4) * 4;
#pragma unroll
  for (int nt = 0; nt < 4; nt++) {
    int ncol = n0 + wn + nt * 16 + fr;
    float bb = bias[ncol];
    size_t cb = (size_t)(m0 + wm + rowq) * DIM + ncol;
#pragma unroll
    for (int mt = 0; mt < 4; mt++)
#pragma unroll
      for (int r = 0; r < 4; r++)
        C[cb + (size_t)(mt * 16 + r) * DIM] = acc[mt][nt][r] + bb;
  }
}

// ---------------------------------------------------------------- flash attention
// ROUND-8 EXACT (83 us, 257.0 total): cvtpk packing, single-buffer,
// 2 barriers/tile, setprio around MFMA clusters. XCD-grouped gid remap.
#define LDA 68

__global__ __launch_bounds__(256, 4) void attention(
    const unsigned short* __restrict__ Qg, const unsigned short* __restrict__ Kg,
    const unsigned short* __restrict__ Vtg, unsigned short* __restrict__ Og) {
  __shared__ unsigned short smem[2 * 64 * 72];   // 18432 B
  unsigned short* sK  = smem;
  unsigned short* sVt = smem + 64 * LDA;

  int gid = blockIdx.x + 16 * (blockIdx.y + 16 * blockIdx.z);  // 0..1023
  int qb   = (gid >> 3) & 15;
  int pair = ((gid & 7) << 3) | (gid >> 7);   // xcd*8 + group
  int h = pair & 15, b = pair >> 4;

  size_t base = (size_t)(b * HEADS + h) * SEQ * DH;
  const unsigned short* Q = Qg + base;
  const unsigned short* K = Kg + base;
  const unsigned short* Vt = Vtg + base;
  int t = threadIdx.x, lane = t & 63, w = t >> 6;
  int m = lane & 31, kh = lane >> 5;
  int q0 = qb * 128 + w * 32;

  bf16x8 qf[4];
#pragma unroll
  for (int kt = 0; kt < 4; kt++)
    qf[kt] = *reinterpret_cast<const bf16x8*>(
        &Q[(size_t)(q0 + m) * DH + kt * 16 + kh * 8]);

  f32x16 oaccT[2];   // [dhalf], C layout: row=d', col=qrow
#pragma unroll
  for (int dh = 0; dh < 2; dh++)
#pragma unroll
    for (int i = 0; i < 16; i++) oaccT[dh][i] = 0.f;
  float rs = 0.f;

  int sr = t >> 2, sc = (t & 3) * 8;

  for (int j0 = 0; j0 < SEQ; j0 += 64) {
    {
      uint4 a0 = *(const uint4*)&K[(size_t)(j0 + sr) * DH + sc];
      uint4 a1 = *(const uint4*)&K[(size_t)(j0 + sr) * DH + sc + 32];
      uint4 b0 = *(const uint4*)&Vt[(size_t)sr * SEQ + j0 + sc];
      uint4 b1 = *(const uint4*)&Vt[(size_t)sr * SEQ + j0 + sc + 32];
      unsigned short* pk0 = &sK[sr * LDA + sc];
      unsigned short* pk1 = &sK[sr * LDA + sc + 32];
      unsigned short* pv0 = &sVt[sr * LDA + sc];
      unsigned short* pv1 = &sVt[sr * LDA + sc + 32];
      *(uint2*)pk0       = make_uint2(a0.x, a0.y);
      *(uint2*)(pk0 + 4) = make_uint2(a0.z, a0.w);
      *(uint2*)pk1       = make_uint2(a1.x, a1.y);
      *(uint2*)(pk1 + 4) = make_uint2(a1.z, a1.w);
      *(uint2*)pv0       = make_uint2(b0.x, b0.y);
      *(uint2*)(pv0 + 4) = make_uint2(b0.z, b0.w);
      *(uint2*)pv1       = make_uint2(b1.x, b1.y);
      *(uint2*)(pv1 + 4) = make_uint2(b1.z, b1.w);
    }
    __syncthreads();

    unsigned int pp[8][2];
#pragma unroll
    for (int jt = 0; jt < 2; jt++) {
      bf16x8 kf[4];
#pragma unroll
      for (int kt = 0; kt < 4; kt++) {
        union { uint2 u[2]; bf16x8 v; } kc;
        const unsigned short* p = &sK[(jt * 32 + m) * LDA + (2 * kt + kh) * 8];
        kc.u[0] = *(const uint2*)p;
        kc.u[1] = *(const uint2*)(p + 4);
        kf[kt] = kc.v;
      }
      f32x16 s;
#pragma unroll
      for (int i = 0; i < 16; i++) s[i] = 0.f;
      __builtin_amdgcn_s_setprio(1);
#pragma unroll
      for (int kt = 0; kt < 4; kt++)
        s = mfma32(kf[kt], qf[kt], s);
      __builtin_amdgcn_s_setprio(0);
      float e[16];
#pragma unroll
      for (int i = 0; i < 16; i++) e[i] = __builtin_amdgcn_exp2f(s[i]);
      float t0 = (e[0] + e[1]) + (e[2] + e[3]);
      float t1 = (e[4] + e[5]) + (e[6] + e[7]);
      float t2 = (e[8] + e[9]) + (e[10] + e[11]);
      float t3 = (e[12] + e[13]) + (e[14] + e[15]);
      rs += (t0 + t1) + (t2 + t3);
#pragma unroll
      for (int sl = 0; sl < 4; sl++) {
        pp[4 * jt + sl][0] = cvtpk(e[4 * sl + 0], e[4 * sl + 1]);
        pp[4 * jt + sl][1] = cvtpk(e[4 * sl + 2], e[4 * sl + 3]);
      }
    }

    __builtin_amdgcn_s_setprio(1);
#pragma unroll
    for (int kb = 0; kb < 4; kb++) {
#pragma unroll
      for (int dh = 0; dh < 2; dh++) {
        union { uint2 u[2]; bf16x8 v; } ac;
        const unsigned short* p = &sVt[(32 * dh + m) * LDA + 16 * kb + 4 * kh];
        ac.u[0] = *(const uint2*)p;
        ac.u[1] = *(const uint2*)(p + 8);
        union { unsigned int u[4]; bf16x8 v; } bc;
        bc.u[0] = pp[2 * kb][0];
        bc.u[1] = pp[2 * kb][1];
        bc.u[2] = pp[2 * kb + 1][0];
        bc.u[3] = pp[2 * kb + 1][1];
        oaccT[dh] = mfma32(ac.v, bc.v, oaccT[dh]);
      }
    }
    __builtin_amdgcn_s_setprio(0);
    __syncthreads();
  }

  float inv;
  {
    float tot = rs + __shfl_xor(rs, 32);
    inv = 1.0f / tot;
  }

  unsigned int* ew = (unsigned int*)smem + (size_t)w * 32 * 36;
#pragma unroll
  for (int dh = 0; dh < 2; dh++)
#pragma unroll
    for (int sl = 0; sl < 4; sl++) {
      unsigned int u0 = cvtpk(oaccT[dh][4 * sl + 0] * inv, oaccT[dh][4 * sl + 1] * inv);
      unsigned int u1 = cvtpk(oaccT[dh][4 * sl + 2] * inv, oaccT[dh][4 * sl + 3] * inv);
      uint2 pk; pk.x = u0; pk.y = u1;
      *(uint2*)&ew[m * 36 + 16 * dh + 4 * sl + 2 * kh] = pk;
    }
  {
    int mr = lane >> 3, ch = lane & 7;
#pragma unroll
    for (int it = 0; it < 4; it++) {
      uint4 vv = *(const uint4*)&ew[(8 * it + mr) * 36 + ch * 4];
      int n = q0 + 8 * it + mr;
      *(uint4*)&Og[((size_t)(b * SEQ + n)) * DIM + h * DH + ch * 8] = vv;
    }
  }
}

// ---------------------------------------------------------------- launch
extern "C" void kernel_launch(void* const* d_in, const int* in_sizes, int n_in,
                              void* d_out, int out_size, void* d_ws, size_t ws_size,
                              hipStream_t stream) {
  const float* x     = (const float*)d_in[0];  // [4,2048,1024]
  const float* w_qkv = (const float*)d_in[1];  // [1024,3072]
  const float* w_out = (const float*)d_in[2];  // [1024,1024]
  const float* b_out = (const float*)d_in[3];  // [1024]
  float* out = (float*)d_out;                  // [4,2048,1024]

  char* ws = (char*)d_ws;
  unsigned short* xb     = (unsigned short*)ws; ws += (size_t)MTOT * DIM * 2;
  unsigned short* wqkv_t = (unsigned short*)ws; ws += (size_t)NQKV * DIM * 2;
  unsigned short* wout_t = (unsigned short*)ws; ws += (size_t)DIM * DIM * 2;
  unsigned short* qb_    = (unsigned short*)ws; ws += (size_t)BATCH * HEADS * SEQ * DH * 2;
  unsigned short* kb_    = (unsigned short*)ws; ws += (size_t)BATCH * HEADS * SEQ * DH * 2;
  unsigned short* vtb_   = (unsigned short*)ws; ws += (size_t)BATCH * HEADS * SEQ * DH * 2;
  unsigned short* attnb  = (unsigned short*)ws; ws += (size_t)MTOT * DIM * 2;

  // 1. casts / transposes
  cast_f32_bf16<<<(MTOT * DIM / 8 + 255) / 256, 256, 0, stream>>>(x, xb, MTOT * DIM / 8);
  transpose_cast<<<dim3(NQKV / 32, DIM / 32), 256, 0, stream>>>(w_qkv, wqkv_t, DIM, NQKV);
  transpose_cast<<<dim3(DIM / 32, DIM / 32), 256, 0, stream>>>(w_out, wout_t, DIM, DIM);

  // 2. QKV projection — Q,K [b,h,n,d]; V TRANSPOSED [b,h,d,n] via LDS-coalesced
  //    epilogue (transpose_v kernel eliminated, stores 64B-coalesced)
  gemm_qkv<<<dim3(NQKV / BN, MTOT / BM), 256, 0, stream>>>(xb, wqkv_t, qb_, kb_, vtb_);

  // 3. flash attention (register-resident P, r8 structure)
  attention<<<dim3(SEQ / 128, HEADS, BATCH), 256, 0, stream>>>(qb_, kb_, vtb_, attnb);

  // 4. output projection + bias
  gemm_out<<<dim3(DIM / BN, MTOT / BM), 256, 0, stream>>>(attnb, wout_t, b_out, out);
}